// Round 9
// baseline (138.253 us; speedup 1.0000x reference)
//
#include <hip/hip_runtime.h>
#include <hip/hip_bf16.h>

// Problem constants
#define NOUT  4096
#define KDIM  1024   // N_SPARSE
#define MROWS 8192   // BATCH*SEQ

typedef __attribute__((ext_vector_type(8))) short bf16x8;    // 8 bf16 = 4 VGPRs
typedef __attribute__((ext_vector_type(16))) float f32x16;   // MFMA 32x32 accumulator

__device__ __forceinline__ unsigned short f2bf(float f) {
  union { float f; unsigned int u; } c; c.f = f;
  unsigned int lsb = (c.u >> 16) & 1u;
  c.u += 0x7fffu + lsb;
  return (unsigned short)(c.u >> 16);
}

__device__ __forceinline__ void gload_lds16(const void* g, void* l) {
  __builtin_amdgcn_global_load_lds(
      (const __attribute__((address_space(1))) void*)g,
      (__attribute__((address_space(3))) void*)l, 16, 0, 0);
}

#define FENCE() asm volatile("" ::: "memory")
#define BAR() do { FENCE(); __builtin_amdgcn_s_barrier(); FENCE(); } while (0)
#define VMW(n) asm volatile("s_waitcnt vmcnt(" #n ")" ::: "memory")

// ---------------------------------------------------------------------------
// Pass 1 (measured-best variant, ~33 us): blocks [0,2048) gather+convert
// 4 x-rows each via LDS row staging; blocks [2048,2560) convert W.
// ---------------------------------------------------------------------------
__global__ __launch_bounds__(512) void prep(const float* __restrict__ x,
                                            const void* __restrict__ idx_raw,
                                            const float* __restrict__ w,
                                            unsigned short* __restrict__ xg,
                                            unsigned short* __restrict__ wb) {
  __shared__ float rows[16384];   // 64 KiB: 4 rows of 4096 f32
  __shared__ int sidx[1024];
  const int b = blockIdx.x;
  const int t = threadIdx.x;

  if (b < 2048) {
    const long long* p64 = (const long long*)idx_raw;
    const int* p32 = (const int*)idx_raw;
    // int64 vs int32 detection: for int32 data, element0-as-int64 >= 2^32
    // (sorted unique indices, second word >= 1), so `< 4096` discriminates.
    const bool is64 = ((unsigned long long)p64[0]) < 4096ull;
    const float* src = x + (size_t)b * 4 * 4096;
#pragma unroll
    for (int i = 0; i < 8; ++i)
      ((float4*)rows)[t + 512 * i] = ((const float4*)src)[t + 512 * i];
    if (is64) {
      sidx[t] = (int)p64[t];
      sidx[t + 512] = (int)p64[t + 512];
    } else {
      sidx[t] = p32[t];
      sidx[t + 512] = p32[t + 512];
    }
    __syncthreads();
    ushort4* dst = (ushort4*)(xg + (size_t)b * 4 * 1024);
#pragma unroll
    for (int i = 0; i < 2; ++i) {
      const int q = t + 512 * i;      // ushort4 index within 4 output rows
      const int e = 4 * q;
      const int rbase = (e >> 10) * 4096;
      const int k = e & 1023;
      ushort4 o;
      o.x = f2bf(rows[rbase + sidx[k + 0]]);
      o.y = f2bf(rows[rbase + sidx[k + 1]]);
      o.z = f2bf(rows[rbase + sidx[k + 2]]);
      o.w = f2bf(rows[rbase + sidx[k + 3]]);
      dst[q] = o;
    }
  } else {
    const int i0 = (b - 2048) * 2048 + t;
#pragma unroll
    for (int j = 0; j < 4; ++j) {
      float4 v = ((const float4*)w)[i0 + 512 * j];
      ushort4 o;
      o.x = f2bf(v.x); o.y = f2bf(v.y); o.z = f2bf(v.z); o.w = f2bf(v.w);
      ((ushort4*)wb)[i0 + 512 * j] = o;
    }
  }
}

// ---------------------------------------------------------------------------
// Pass 2: 128x128 tile, BK=32, 256 threads (4 waves, 2x2; per-wave 64x64 on
// 32x32 MFMA), LDS 32 KiB double-buffered -> 4 blocks/CU (~4 waves/SIMD).
// Co-resident blocks' async phases hide each other's barrier/ds_read stalls
// (the m97 TLP mechanism). Loop: STAGE(next) -> VMW(4) -> BAR -> ds_read +
// 8 MFMA/wave -> BAR.
//
// GRID FIX vs round 8: 2048 blocks (64 M-tiles x 32 N-tiles); round 8
// launched 1024 and left rows 4096..8191 unwritten.
//
// LDS swizzle (64B rows, 4 granules of 16B): granule' = c ^ ((row>>1)&3).
// A 16-lane read group (rows R..R+15, fixed c) hits each granule-slot mod 8
// exactly twice -> 2-way = free (m136). Write side per rule #21: linear
// gload_lds dest (slot = tid), inverse-permuted global source
// (c = (t&3) ^ ((t>>3)&3)); round-trip verified.
// ---------------------------------------------------------------------------
__global__ __launch_bounds__(256, 4) void gemm128(const unsigned short* __restrict__ A,
                                                  const unsigned short* __restrict__ B,
                                                  float* __restrict__ C) {
  __shared__ __align__(16) unsigned short lds[16384];  // 32 KiB: 2 bufs x (A 8K | B 8K)

  const int tid = threadIdx.x;
  const int lane = tid & 63;
  const int wid = tid >> 6;
  const int wm = wid >> 1, wn = wid & 1;       // 2 x 2 wave grid, per-wave 64x64
  const int l31 = lane & 31, lh = lane >> 5;   // 32x32 frag: row, k-half

  // T1 XCD swizzle: 2048 blocks = 8 XCDs x 256 contiguous (bijective,
  // 2048%8==0). Within an XCD: 8 bm-slabs x 32 bn, bn-major -> one bm-slab's
  // A (256 KB) stays L2-resident across its 32 consecutive blocks.
  const int bid = blockIdx.x;
  const int swz = (bid & 7) * 256 + (bid >> 3);
  const int bm0 = (swz >> 5) * 128;   // 0..63 M-tiles
  const int bn0 = (swz & 31) * 128;   // 0..31 N-tiles

  // ---- staging map: thread t owns linear 16B slot t per half-tile (64 rows);
  // row r = t>>2, lds-granule g = t&3, global k-octet c = g ^ ((t>>3)&3).
  const int rS = tid >> 2;
  const int cS = (tid & 3) ^ ((tid >> 3) & 3);
  const unsigned short* Ag = A + (size_t)(bm0 + rS) * KDIM + cS * 8;
  const unsigned short* Bg = B + (size_t)(bn0 + rS) * KDIM + cS * 8;
  const int tid8 = tid * 8;

  // ---- ds_read map: element (row R, octet c) at ushort offset
  // R*32 + (c ^ ((R>>1)&3))*8. Frag rows = base32 + l31 -> XOR = (l31>>1)&3.
  const int sw = (l31 >> 1) & 3;
  const int cK0 = (lh ^ sw) * 8;      // kb=0 (octet = 2*kb + lh)
  const int cK1 = cK0 ^ 16;           // kb=1
  const int aOff = (wm * 64 + l31) * 32;            // + mf*1024 (+ d*8192)
  const int bOff = 4096 + (wn * 64 + l31) * 32;     // + nf*1024

  f32x16 acc[2][2] = {};

#define STAGE(d, t) do {                                              \
    unsigned short* Lb = lds + (d) * 8192;                            \
    gload_lds16(Ag + (t) * 32,              Lb + tid8);               \
    gload_lds16(Ag + 64 * KDIM + (t) * 32,  Lb + 2048 + tid8);        \
    gload_lds16(Bg + (t) * 32,              Lb + 4096 + tid8);        \
    gload_lds16(Bg + 64 * KDIM + (t) * 32,  Lb + 6144 + tid8);        \
  } while (0)

  STAGE(0, 0);

  for (int t = 0; t < 32; ++t) {
    const int d = t & 1;
    if (t < 31) {
      STAGE(d ^ 1, t + 1);   // prefetch next K-tile into other buffer
      VMW(4);                // current tile landed; next tile's 4 in flight
    } else {
      VMW(0);
    }
    BAR();
    const unsigned short* La = lds + d * 8192;
    bf16x8 b0[2], b1[2];
    b0[0] = *(const bf16x8*)(La + bOff + cK0);
    b0[1] = *(const bf16x8*)(La + bOff + cK1);
    b1[0] = *(const bf16x8*)(La + bOff + 1024 + cK0);
    b1[1] = *(const bf16x8*)(La + bOff + 1024 + cK1);
    __builtin_amdgcn_s_setprio(1);
#pragma unroll
    for (int mf = 0; mf < 2; ++mf) {
      bf16x8 a0 = *(const bf16x8*)(La + aOff + mf * 1024 + cK0);
      bf16x8 a1 = *(const bf16x8*)(La + aOff + mf * 1024 + cK1);
      acc[mf][0] = __builtin_amdgcn_mfma_f32_32x32x16_bf16(a0, b0[0], acc[mf][0], 0, 0, 0);
      acc[mf][0] = __builtin_amdgcn_mfma_f32_32x32x16_bf16(a1, b0[1], acc[mf][0], 0, 0, 0);
      acc[mf][1] = __builtin_amdgcn_mfma_f32_32x32x16_bf16(a0, b1[0], acc[mf][1], 0, 0, 0);
      acc[mf][1] = __builtin_amdgcn_mfma_f32_32x32x16_bf16(a1, b1[1], acc[mf][1], 0, 0, 0);
    }
    __builtin_amdgcn_s_setprio(0);
    BAR();   // protect this buffer from next iteration's prefetch overwrite
  }
#undef STAGE

  // Epilogue. 32x32 C/D (m74/m101): col = lane&31,
  // row = (reg&3) + 8*(reg>>2) + 4*(lane>>5).
  float* base = C + (size_t)(bm0 + wm * 64) * NOUT + bn0 + wn * 64;
#pragma unroll
  for (int mf = 0; mf < 2; ++mf)
#pragma unroll
    for (int nf = 0; nf < 2; ++nf) {
      f32x16 v = acc[mf][nf];
#pragma unroll
      for (int r = 0; r < 16; ++r) {
        const int rowi = mf * 32 + (r & 3) + 8 * (r >> 2) + 4 * lh;
        base[(size_t)rowi * NOUT + nf * 32 + l31] = v[r];
      }
    }
}

extern "C" void kernel_launch(void* const* d_in, const int* in_sizes, int n_in,
                              void* d_out, int out_size, void* d_ws, size_t ws_size,
                              hipStream_t stream) {
  const float* x   = (const float*)d_in[0];   // [4,2048,4096] f32
  const float* sv  = (const float*)d_in[1];   // [4096,1024] f32
  const void*  idx = d_in[2];                 // [1024] int32 or int64
  float* out = (float*)d_out;                 // [4,2048,4096] f32

  unsigned short* xg = (unsigned short*)d_ws;                 // [8192,1024] bf16
  unsigned short* wb = xg + (size_t)MROWS * KDIM;             // [4096,1024] bf16

  prep<<<2560, 512, 0, stream>>>(x, idx, sv, xg, wb);

  gemm128<<<2048, 256, 0, stream>>>(xg, wb, out);  // 64 M x 32 N tiles
}